// Round 4
// baseline (262.450 us; speedup 1.0000x reference)
//
#include <hip/hip_runtime.h>
#include <hip/hip_bf16.h>
#include <math.h>

// ---- problem constants ----
#define BB     256
#define TT     64
#define BT     (BB*TT)      // 16384 tokens
#define XD     44
#define XP     40
#define XS     10
#define HID    128
#define XEMB   32
#define NHID   8
#define NAG    10
#define NEDGE  90
#define GEMB   720          // NHID*NEDGE
#define KF     768          // padded fused feature dim (763 -> 768)
#define NTOT   640          // 128 (a) + 128 (o) + 384 (ih)

typedef __bf16  bf16_t;
typedef __bf16  bf16x8 __attribute__((ext_vector_type(8)));
typedef float   floatx4 __attribute__((ext_vector_type(4)));
typedef _Float16 half2_t __attribute__((ext_vector_type(2)));

__device__ __forceinline__ float elu_f(float v) { return v > 0.f ? v : expm1f(v); }
__device__ __forceinline__ float rcp_fast(float x) { return __builtin_amdgcn_rcpf(x); }
__device__ __forceinline__ float sigmoid_fast(float v) { return rcp_fast(1.f + __expf(-v)); }
// inf-safe fast tanh: x->+inf => 1, x->-inf => -1
__device__ __forceinline__ float tanh_fast(float x) { return 1.f - 2.f * rcp_fast(1.f + __expf(2.f * x)); }

// ---------------------------------------------------------------------------
// Kernel 1: build Wcat^T (n-major, k-contiguous) bf16 + fused bias (fp32)
// F feature layout: [0:32) xemb | [32:42) demo | [42] treat | [43:763) gemb | [763:768) pad0
// ---------------------------------------------------------------------------
__global__ __launch_bounds__(256) void prep_kernel(
    const float* __restrict__ Wa1, const float* __restrict__ ba1,
    const float* __restrict__ Wo1, const float* __restrict__ bo1,
    const float* __restrict__ Wih, const float* __restrict__ bih,
    bf16_t* __restrict__ WT, float* __restrict__ bcat) {
  int idx = blockIdx.x * 256 + threadIdx.x;
  if (idx >= NTOT * KF) return;
  int n = idx / KF, k = idx - n * KF;
  float v = 0.f;
  if (n < 128) {                       // W_a1: a_in = [demo(10), gemb(720)]
    if (k >= 32 && k < 42)        v = Wa1[n * 730 + (k - 32)];
    else if (k >= 43 && k < 763)  v = Wa1[n * 730 + 10 + (k - 43)];
  } else if (n < 256) {                // W_o1: o_in == F[0:763] exactly
    int m = n - 128;
    if (k < 763)                  v = Wo1[m * 763 + k];
  } else {                             // W_ih: rnn_in = [xemb(32), treat(1), gemb(720)]
    int m = n - 256;
    if (k < 32)                   v = Wih[m * 753 + k];
    else if (k == 42)             v = Wih[m * 753 + 32];
    else if (k >= 43 && k < 763)  v = Wih[m * 753 + 33 + (k - 43)];
  }
  WT[n * KF + k] = (bf16_t)v;
  if (k == 0) {
    bcat[n] = (n < 128) ? ba1[n] : (n < 256 ? bo1[n - 128] : bih[n - 256]);
  }
}

// ---------------------------------------------------------------------------
// Kernel 2: per-token graph-net encoder -> F (bf16, 16384 x 768)
// one wave per block; 8 tokens per block (weights loaded once, demo hoisted)
// ---------------------------------------------------------------------------
#define W_M1A 0
#define B_M1A 32
#define W_M1B 40
#define B_M1B 104
#define W_M2A 112
#define B_M2A 240
#define W_M2B 248
#define B_M2B 312
#define W_X2E 320
#define B_X2E 448
#define W_ST  480
#define B_ST  580
#define W_TOT 590
#define TOKS_PER_BLK 8

__global__ __launch_bounds__(64) void encoder_kernel(
    const float* __restrict__ x, const float* __restrict__ x_demo,
    const float* __restrict__ ftreat,
    const float* __restrict__ Wm1a, const float* __restrict__ bm1a,
    const float* __restrict__ Wm1b, const float* __restrict__ bm1b,
    const float* __restrict__ Wm2a, const float* __restrict__ bm2a,
    const float* __restrict__ Wm2b, const float* __restrict__ bm2b,
    const float* __restrict__ Wx2e, const float* __restrict__ bx2e,
    const float* __restrict__ Wst, const float* __restrict__ bst,
    bf16_t* __restrict__ F) {
  int blk = blockIdx.x;                  // 0..2047
  int b = blk >> 3, tc = blk & 7;        // batch, token-chunk
  int tid = threadIdx.x;

  __shared__ float w[W_TOT];
  __shared__ float demoL[XS];
  __shared__ float xl[XD];
  __shared__ float h1a[NAG * 8];
  __shared__ float h1s[NAG * 8];
  __shared__ float h2a[NEDGE * 8];

  for (int i = tid; i < 32;  i += 64) w[W_M1A + i] = Wm1a[i];
  for (int i = tid; i < 8;   i += 64) w[B_M1A + i] = bm1a[i];
  for (int i = tid; i < 64;  i += 64) w[W_M1B + i] = Wm1b[i];
  for (int i = tid; i < 8;   i += 64) w[B_M1B + i] = bm1b[i];
  for (int i = tid; i < 128; i += 64) w[W_M2A + i] = Wm2a[i];
  for (int i = tid; i < 8;   i += 64) w[B_M2A + i] = bm2a[i];
  for (int i = tid; i < 64;  i += 64) w[W_M2B + i] = Wm2b[i];
  for (int i = tid; i < 8;   i += 64) w[B_M2B + i] = bm2b[i];
  for (int i = tid; i < 128; i += 64) w[W_X2E + i] = Wx2e[i];
  for (int i = tid; i < 32;  i += 64) w[B_X2E + i] = bx2e[i];
  for (int i = tid; i < 100; i += 64) w[W_ST + i]  = Wst[i];
  for (int i = tid; i < 10;  i += 64) w[B_ST + i]  = bst[i];
  __syncthreads();

  // demo (per-b, shared by all tokens of this block)
  if (tid < 10) {
    float s = w[B_ST + tid];
#pragma unroll
    for (int j = 0; j < 10; j++) s += x_demo[b * XS + j] * w[W_ST + tid * 10 + j];
    demoL[tid] = s;
  }
  __syncthreads();

  for (int ti = 0; ti < TOKS_PER_BLK; ti++) {
    int t = tc * TOKS_PER_BLK + ti;
    int tok = b * TT + t;
    if (tid < XD) xl[tid] = x[(size_t)(b * 65 + t) * XD + tid];
    __syncthreads();

    // h1a = elu(xa @ Wm1a^T + b)
    for (int c = tid; c < NAG * 8; c += 64) {
      int i = c >> 3, o = c & 7;
      float s = w[B_M1A + o];
#pragma unroll
      for (int f = 0; f < 4; f++) s += xl[i * 4 + f] * w[W_M1A + o * 4 + f];
      h1a[c] = elu_f(s);
    }
    __syncthreads();
    // h1 = elu(h1a @ Wm1b^T + b)
    for (int c = tid; c < NAG * 8; c += 64) {
      int i = c >> 3, o = c & 7;
      float s = w[B_M1B + o];
#pragma unroll
      for (int p = 0; p < 8; p++) s += h1a[i * 8 + p] * w[W_M1B + o * 8 + p];
      h1s[c] = elu_f(s);
    }
    __syncthreads();
    // h2a = elu(edges @ Wm2a^T + b)
    for (int c = tid; c < NEDGE * 8; c += 64) {
      int e = c >> 3, o = c & 7;
      int r = e / 9, q = e - 9 * r;
      int sd = q + (q >= r ? 1 : 0);
      float s = w[B_M2A + o];
#pragma unroll
      for (int kk = 0; kk < 8; kk++) s += h1s[r * 8 + kk]  * w[W_M2A + o * 16 + kk];
#pragma unroll
      for (int kk = 0; kk < 8; kk++) s += h1s[sd * 8 + kk] * w[W_M2A + o * 16 + 8 + kk];
      h2a[c] = elu_f(s);
    }
    __syncthreads();

    bf16_t* Frow = F + (size_t)tok * KF;
    // gemb = elu(h2a @ Wm2b^T + b) -> F[43:763)
    for (int c = tid; c < NEDGE * 8; c += 64) {
      int e = c >> 3, o = c & 7;
      float s = w[B_M2B + o];
#pragma unroll
      for (int kk = 0; kk < 8; kk++) s += h2a[e * 8 + kk] * w[W_M2B + o * 8 + kk];
      Frow[43 + c] = (bf16_t)elu_f(s);
    }
    // xemb -> F[0:32)
    if (tid < 32) {
      float s = w[B_X2E + tid];
#pragma unroll
      for (int f = 0; f < 4; f++) s += xl[40 + f] * w[W_X2E + tid * 4 + f];
      Frow[tid] = (bf16_t)s;
    } else if (tid < 42) {               // demo -> F[32:42)
      Frow[tid] = (bf16_t)demoL[tid - 32];
    } else if (tid == 42) {              // treat -> F[42]
      Frow[42] = (bf16_t)ftreat[b * 65 + t];
    } else if (tid < 48) {               // pad -> F[763:768) = 0
      Frow[720 + tid] = (bf16_t)0.f;
    }
    __syncthreads();   // protect xl/h arrays before next token overwrites
  }
}

// ---------------------------------------------------------------------------
// Kernel 3: G[16384,640] = F[16384,768] @ WT^T + bcat  (bf16 MFMA, fp32 acc)
// 128x128 block tile, 4 waves each 64x64, 16x16x32 bf16, BK=32
// ---------------------------------------------------------------------------
__global__ __launch_bounds__(256) void gemm_kernel(
    const bf16_t* __restrict__ F, const bf16_t* __restrict__ WT,
    const float* __restrict__ bcat, float* __restrict__ G) {
  __shared__ __align__(16) bf16_t As[128 * 32];
  __shared__ __align__(16) bf16_t Bs[128 * 32];

  int tid  = threadIdx.x;
  int lane = tid & 63;
  int wv   = tid >> 6;
  int wr   = wv >> 1, wc = wv & 1;
  int m0 = blockIdx.x * 128, n0 = blockIdx.y * 128;

  floatx4 acc[4][4];
#pragma unroll
  for (int i = 0; i < 4; i++)
#pragma unroll
    for (int j = 0; j < 4; j++) acc[i][j] = floatx4{0.f, 0.f, 0.f, 0.f};

  int c0 = tid, c1 = tid + 256;          // 16B chunks: row=c>>2, kp=c&3
  int r0 = c0 >> 2, p0 = c0 & 3;
  int r1 = c1 >> 2, p1 = c1 & 3;
  int qr = lane >> 4;                    // k-quad
  int lr = lane & 15;                    // m/n within tile

  for (int k0 = 0; k0 < KF; k0 += 32) {
    uint4 a0 = *(const uint4*)(F  + (size_t)(m0 + r0) * KF + k0 + p0 * 8);
    uint4 a1 = *(const uint4*)(F  + (size_t)(m0 + r1) * KF + k0 + p1 * 8);
    uint4 b0 = *(const uint4*)(WT + (size_t)(n0 + r0) * KF + k0 + p0 * 8);
    uint4 b1 = *(const uint4*)(WT + (size_t)(n0 + r1) * KF + k0 + p1 * 8);
    __syncthreads();
    ((uint4*)As)[c0] = a0; ((uint4*)As)[c1] = a1;
    ((uint4*)Bs)[c0] = b0; ((uint4*)Bs)[c1] = b1;
    __syncthreads();

    bf16x8 af[4], bf[4];
#pragma unroll
    for (int i = 0; i < 4; i++) {
      af[i] = *(const bf16x8*)(As + (wr * 64 + i * 16 + lr) * 32 + qr * 8);
      bf[i] = *(const bf16x8*)(Bs + (wc * 64 + i * 16 + lr) * 32 + qr * 8);
    }
#pragma unroll
    for (int i = 0; i < 4; i++)
#pragma unroll
      for (int j = 0; j < 4; j++)
        acc[i][j] = __builtin_amdgcn_mfma_f32_16x16x32_bf16(af[i], bf[j], acc[i][j], 0, 0, 0);
  }

  // epilogue: add bias, store fp32. C/D map: col=lane&15, row=(lane>>4)*4+reg
#pragma unroll
  for (int i = 0; i < 4; i++) {
#pragma unroll
    for (int j = 0; j < 4; j++) {
      int col = n0 + wc * 64 + j * 16 + lr;
      float bv = bcat[col];
#pragma unroll
      for (int r = 0; r < 4; r++) {
        int row = m0 + wr * 64 + i * 16 + qr * 4 + r;
        G[(size_t)row * NTOT + col] = acc[i][j][r] + bv;
      }
    }
  }
}

// ---------------------------------------------------------------------------
// Kernel 4: heads — a_out / y_out (one wave per token)
// ---------------------------------------------------------------------------
__global__ __launch_bounds__(256) void head_kernel(
    const float* __restrict__ G, const float* __restrict__ Wa2,
    const float* __restrict__ Wo2, float* __restrict__ out) {
  int wid  = (blockIdx.x * 256 + threadIdx.x) >> 6;   // token
  int lane = threadIdx.x & 63;
  const float* g = G + (size_t)wid * NTOT;
  float sa = fmaxf(g[lane], 0.f) * Wa2[lane] + fmaxf(g[lane + 64], 0.f) * Wa2[lane + 64];
  float sy = fmaxf(g[128 + lane], 0.f) * Wo2[lane] + fmaxf(g[192 + lane], 0.f) * Wo2[lane + 64];
#pragma unroll
  for (int off = 32; off > 0; off >>= 1) {
    sa += __shfl_down(sa, off, 64);
    sy += __shfl_down(sy, off, 64);
  }
  if (lane == 0) {
    out[(size_t)wid * 130 + 0] = sa;
    out[(size_t)wid * 130 + 1] = sy;
  }
}

// ---------------------------------------------------------------------------
// Kernel 5: GRU — 1 block (128 threads, 2 waves) per sequence.
// Thread j owns W_hh rows {j, 128+j, 256+j} pair-packed half2 in VGPRs
// (192 VGPRs) and computes gates for hidden unit j LOCALLY — no gh exchange.
// h crosses waves via double-buffered packed-half2 LDS: one ds_read_b32 +
// readlane broadcast per step; ONE barrier per step. The out store and the
// gi(t+1) prefetch are placed so their compiler-forced vmcnt(0) drain at the
// barrier lands one step later, covered by the ~560cy matvec.
// ---------------------------------------------------------------------------
__global__ __launch_bounds__(128, 2) void gru_kernel(
    const float* __restrict__ G, const float* __restrict__ h0,
    const float* __restrict__ Whh, const float* __restrict__ bhh,
    float* __restrict__ out) {
  int b = blockIdx.x;
  int tid = threadIdx.x;          // 0..127 == hidden unit j
  int lane = tid & 63;

  __shared__ unsigned int h2[2][HID / 2];   // packed half2: (h[2l], h[2l+1])

  const float* gbase = G + (size_t)b * TT * NTOT;

  // rows {tid, 128+tid, 256+tid} of W_hh, pair-packed f16
  half2_t wr[64], wz[64], wn[64];
#pragma unroll
  for (int l = 0; l < 64; l++) {
    float2 a = *(const float2*)(Whh + (size_t)tid * HID + 2 * l);
    wr[l] = half2_t{(_Float16)a.x, (_Float16)a.y};
  }
#pragma unroll
  for (int l = 0; l < 64; l++) {
    float2 a = *(const float2*)(Whh + (size_t)(HID + tid) * HID + 2 * l);
    wz[l] = half2_t{(_Float16)a.x, (_Float16)a.y};
  }
#pragma unroll
  for (int l = 0; l < 64; l++) {
    float2 a = *(const float2*)(Whh + (size_t)(2 * HID + tid) * HID + 2 * l);
    wn[l] = half2_t{(_Float16)a.x, (_Float16)a.y};
  }
  float br = bhh[tid], bz = bhh[HID + tid], bn = bhh[2 * HID + tid];

  float hprev = h0[(size_t)b * HID + tid];
  ((_Float16*)h2[0])[tid] = (_Float16)hprev;
  float ir = gbase[256 + tid], iz = gbase[384 + tid], inn = gbase[512 + tid];
  __syncthreads();

  for (int t = 0; t < TT; t++) {
    unsigned int hl = h2[t & 1][lane];   // one b32/lane -> all 128 h via readlane
    float nir = 0.f, niz = 0.f, ninn = 0.f;
    if (t + 1 < TT) {                    // prefetch: drains at NEXT barrier
      const float* gn = gbase + (size_t)(t + 1) * NTOT;
      nir  = gn[256 + tid];
      niz  = gn[384 + tid];
      ninn = gn[512 + tid];
    }
    float sr0 = 0.f, sr1 = 0.f, sz0 = 0.f, sz1 = 0.f, sn0 = 0.f, sn1 = 0.f;
#pragma unroll
    for (int l = 0; l < 64; l += 2) {
      int p0 = __builtin_amdgcn_readlane((int)hl, l);
      int p1 = __builtin_amdgcn_readlane((int)hl, l + 1);
      half2_t q0 = __builtin_bit_cast(half2_t, p0);
      half2_t q1 = __builtin_bit_cast(half2_t, p1);
      sr0 = __builtin_amdgcn_fdot2(wr[l],     q0, sr0, false);
      sr1 = __builtin_amdgcn_fdot2(wr[l + 1], q1, sr1, false);
      sz0 = __builtin_amdgcn_fdot2(wz[l],     q0, sz0, false);
      sz1 = __builtin_amdgcn_fdot2(wz[l + 1], q1, sz1, false);
      sn0 = __builtin_amdgcn_fdot2(wn[l],     q0, sn0, false);
      sn1 = __builtin_amdgcn_fdot2(wn[l + 1], q1, sn1, false);
    }
    float r  = sigmoid_fast(ir + sr0 + sr1 + br);
    float z  = sigmoid_fast(iz + sz0 + sz1 + bz);
    float nn = tanh_fast(inn + r * (sn0 + sn1 + bn));
    float hn = (1.f - z) * nn + z * hprev;
    hprev = hn;
    ((_Float16*)h2[(t + 1) & 1])[tid] = (_Float16)hn;
    __syncthreads();
    // store AFTER the barrier: its vmcnt(0) drain lands at the next barrier
    out[(size_t)(b * TT + t) * 130 + 2 + tid] = hn;
    ir = nir; iz = niz; inn = ninn;
  }
}

// ---------------------------------------------------------------------------
extern "C" void kernel_launch(void* const* d_in, const int* in_sizes, int n_in,
                              void* d_out, int out_size, void* d_ws, size_t ws_size,
                              hipStream_t stream) {
  const float* x      = (const float*)d_in[0];
  const float* x_demo = (const float*)d_in[1];
  const float* ftr    = (const float*)d_in[2];
  const float* h0     = (const float*)d_in[3];
  const float* Wx2e   = (const float*)d_in[4];
  const float* bx2e   = (const float*)d_in[5];
  const float* Wst    = (const float*)d_in[6];
  const float* bst    = (const float*)d_in[7];
  const float* Wm1a   = (const float*)d_in[8];
  const float* bm1a   = (const float*)d_in[9];
  const float* Wm1b   = (const float*)d_in[10];
  const float* bm1b   = (const float*)d_in[11];
  const float* Wm2a   = (const float*)d_in[12];
  const float* bm2a   = (const float*)d_in[13];
  const float* Wm2b   = (const float*)d_in[14];
  const float* bm2b   = (const float*)d_in[15];
  const float* Wa1    = (const float*)d_in[16];
  const float* ba1    = (const float*)d_in[17];
  const float* Wa2    = (const float*)d_in[18];
  const float* Wo1    = (const float*)d_in[19];
  const float* bo1    = (const float*)d_in[20];
  const float* Wo2    = (const float*)d_in[21];
  const float* Wih    = (const float*)d_in[22];
  const float* bih    = (const float*)d_in[23];
  const float* Whh    = (const float*)d_in[24];
  const float* bhh    = (const float*)d_in[25];
  float* out = (float*)d_out;

  char* ws = (char*)d_ws;
  bf16_t* F   = (bf16_t*)(ws);                             // 16384*768*2 = 25165824
  bf16_t* WT  = (bf16_t*)(ws + 25165824);                  // 640*768*2   = 983040
  float*  bc  = (float*)(ws + 25165824 + 983040);          // 640*4       = 2560
  float*  G   = (float*)(ws + 25165824 + 983040 + 2560);   // 16384*640*4 = 41943040

  prep_kernel<<<dim3((NTOT * KF + 255) / 256), dim3(256), 0, stream>>>(
      Wa1, ba1, Wo1, bo1, Wih, bih, WT, bc);
  encoder_kernel<<<dim3(BT / TOKS_PER_BLK), dim3(64), 0, stream>>>(
      x, x_demo, ftr, Wm1a, bm1a, Wm1b, bm1b, Wm2a, bm2a, Wm2b, bm2b,
      Wx2e, bx2e, Wst, bst, F);
  gemm_kernel<<<dim3(BT / 128, NTOT / 128), dim3(256), 0, stream>>>(F, WT, bc, G);
  head_kernel<<<dim3(BT / 4), dim3(256), 0, stream>>>(G, Wa2, Wo2, out);
  gru_kernel<<<dim3(BB), dim3(128), 0, stream>>>(G, h0, Whh, bhh, out);
}

// Round 5
// 227.534 us; speedup vs baseline: 1.1535x; 1.1535x over previous
//
#include <hip/hip_runtime.h>
#include <hip/hip_bf16.h>
#include <math.h>

// ---- problem constants ----
#define BB     256
#define TT     64
#define BT     (BB*TT)      // 16384 tokens
#define XD     44
#define XP     40
#define XS     10
#define HID    128
#define XEMB   32
#define NHID   8
#define NAG    10
#define NEDGE  90
#define GEMB   720          // NHID*NEDGE
#define KF     768          // padded fused feature dim
#define NTOT   640          // 128 (a) + 128 (o) + 384 (ih)

// F feature layout (v2): [0:32) xemb | [32:42) demo | [42] treat | [43:48) pad0 | [48:768) gemb

typedef __bf16  bf16_t;
typedef __bf16  bf16x8 __attribute__((ext_vector_type(8)));
typedef float   floatx4 __attribute__((ext_vector_type(4)));
typedef _Float16 half2_t __attribute__((ext_vector_type(2)));
typedef _Float16 half4_t __attribute__((ext_vector_type(4)));
typedef _Float16 half8_t __attribute__((ext_vector_type(8)));

__device__ __forceinline__ float rcp_fast(float x) { return __builtin_amdgcn_rcpf(x); }
__device__ __forceinline__ float sigmoid_fast(float v) { return rcp_fast(1.f + __expf(-v)); }
__device__ __forceinline__ float tanh_fast(float x) { return 1.f - 2.f * rcp_fast(1.f + __expf(2.f * x)); }
__device__ __forceinline__ float elu_fast(float v) { return v > 0.f ? v : __expf(v) - 1.f; }
__device__ __forceinline__ float fdot2f(half2_t a, half2_t b, float acc) {
  return __builtin_amdgcn_fdot2(a, b, acc, false);
}
__device__ __forceinline__ float dot8h(half8_t a, half8_t b, float acc) {
  acc = fdot2f(half2_t{a[0], a[1]}, half2_t{b[0], b[1]}, acc);
  acc = fdot2f(half2_t{a[2], a[3]}, half2_t{b[2], b[3]}, acc);
  acc = fdot2f(half2_t{a[4], a[5]}, half2_t{b[4], b[5]}, acc);
  acc = fdot2f(half2_t{a[6], a[7]}, half2_t{b[6], b[7]}, acc);
  return acc;
}

// ---------------------------------------------------------------------------
// Kernel 1: build Wcat^T (n-major, k-contiguous) bf16 + fused bias (fp32)
// ---------------------------------------------------------------------------
__global__ __launch_bounds__(256) void prep_kernel(
    const float* __restrict__ Wa1, const float* __restrict__ ba1,
    const float* __restrict__ Wo1, const float* __restrict__ bo1,
    const float* __restrict__ Wih, const float* __restrict__ bih,
    bf16_t* __restrict__ WT, float* __restrict__ bcat) {
  int idx = blockIdx.x * 256 + threadIdx.x;
  if (idx >= NTOT * KF) return;
  int n = idx / KF, k = idx - n * KF;
  float v = 0.f;
  if (n < 128) {                       // W_a1: a_in = [demo(10), gemb(720)]
    if (k >= 32 && k < 42)  v = Wa1[n * 730 + (k - 32)];
    else if (k >= 48)       v = Wa1[n * 730 + 10 + (k - 48)];
  } else if (n < 256) {                // W_o1: o_in = [xemb, demo, treat, gemb]
    int m = n - 128;
    if (k < 43)             v = Wo1[m * 763 + k];
    else if (k >= 48)       v = Wo1[m * 763 + 43 + (k - 48)];
  } else {                             // W_ih: rnn_in = [xemb(32), treat(1), gemb(720)]
    int m = n - 256;
    if (k < 32)             v = Wih[m * 753 + k];
    else if (k == 42)       v = Wih[m * 753 + 32];
    else if (k >= 48)       v = Wih[m * 753 + 33 + (k - 48)];
  }
  WT[n * KF + k] = (bf16_t)v;
  if (k == 0) {
    bcat[n] = (n < 128) ? ba1[n] : (n < 256 ? bo1[n - 128] : bih[n - 256]);
  }
}

// ---------------------------------------------------------------------------
// Kernel 2: encoder v3 — one wave per block, 4 tokens/block, packed-f16 dot2.
// Stage1: lane a (<10) computes h1a->h1 for agent a fully in registers,
//         writes one packed ds_write_b128.
// Stage2+gemb FUSED: lane handles edge e (and e+64): 2 ds_read_b128 of h1s,
//         8 h2a outputs in regs -> gemb 8 outputs -> one 16B global store.
// LDS instrs/token: ~5 (vs ~600 in v2). No bank-conflict-prone scalar reads.
// ---------------------------------------------------------------------------
__global__ __launch_bounds__(64) void encoder_kernel(
    const float* __restrict__ x, const float* __restrict__ x_demo,
    const float* __restrict__ ftreat,
    const float* __restrict__ Wm1a, const float* __restrict__ bm1a,
    const float* __restrict__ Wm1b, const float* __restrict__ bm1b,
    const float* __restrict__ Wm2a, const float* __restrict__ bm2a,
    const float* __restrict__ Wm2b, const float* __restrict__ bm2b,
    const float* __restrict__ Wx2e, const float* __restrict__ bx2e,
    const float* __restrict__ Wst, const float* __restrict__ bst,
    bf16_t* __restrict__ F) {
  int blk = blockIdx.x;                 // 0..4095
  int b = blk >> 4, tc = blk & 15;      // batch, 4-token chunk
  int lane = threadIdx.x;

  __shared__ __align__(16) _Float16 h1sp[NAG * 8];
  __shared__ __align__(16) _Float16 w2aR[64];
  __shared__ __align__(16) _Float16 w2aS[64];
  __shared__ __align__(16) _Float16 w2bp[64];
  __shared__ float demoL[XS];

  // ---- per-block init: pack stage2/gemb weights to LDS (f16) ----
  if (lane < 8) {
    float4 v0 = *(const float4*)(Wm2a + lane * 16);
    float4 v1 = *(const float4*)(Wm2a + lane * 16 + 4);
    float4 v2 = *(const float4*)(Wm2a + lane * 16 + 8);
    float4 v3 = *(const float4*)(Wm2a + lane * 16 + 12);
    *(half8_t*)&w2aR[lane * 8] = half8_t{
        (_Float16)v0.x, (_Float16)v0.y, (_Float16)v0.z, (_Float16)v0.w,
        (_Float16)v1.x, (_Float16)v1.y, (_Float16)v1.z, (_Float16)v1.w};
    *(half8_t*)&w2aS[lane * 8] = half8_t{
        (_Float16)v2.x, (_Float16)v2.y, (_Float16)v2.z, (_Float16)v2.w,
        (_Float16)v3.x, (_Float16)v3.y, (_Float16)v3.z, (_Float16)v3.w};
    float4 u0 = *(const float4*)(Wm2b + lane * 8);
    float4 u1 = *(const float4*)(Wm2b + lane * 8 + 4);
    *(half8_t*)&w2bp[lane * 8] = half8_t{
        (_Float16)u0.x, (_Float16)u0.y, (_Float16)u0.z, (_Float16)u0.w,
        (_Float16)u1.x, (_Float16)u1.y, (_Float16)u1.z, (_Float16)u1.w};
  }
  if (lane < 10) {
    float s = bst[lane];
#pragma unroll
    for (int j = 0; j < 10; j++) s += x_demo[b * XS + j] * Wst[lane * 10 + j];
    demoL[lane] = s;
  }

  // stage1 weights in regs (wave-uniform)
  half4_t wA[8]; float bA[8];
  half8_t wB1[8]; float bB1[8];
  float bR[8], bG[8];
#pragma unroll
  for (int o = 0; o < 8; o++) {
    float4 v = *(const float4*)(Wm1a + o * 4);
    wA[o] = half4_t{(_Float16)v.x, (_Float16)v.y, (_Float16)v.z, (_Float16)v.w};
    bA[o] = bm1a[o];
    float4 w0 = *(const float4*)(Wm1b + o * 8);
    float4 w1 = *(const float4*)(Wm1b + o * 8 + 4);
    wB1[o] = half8_t{(_Float16)w0.x, (_Float16)w0.y, (_Float16)w0.z, (_Float16)w0.w,
                     (_Float16)w1.x, (_Float16)w1.y, (_Float16)w1.z, (_Float16)w1.w};
    bB1[o] = bm1b[o];
    bR[o] = bm2a[o];
    bG[o] = bm2b[o];
  }
  half4_t wX; float bX;
  {
    float4 v = *(const float4*)(Wx2e + (lane & 31) * 4);
    wX = half4_t{(_Float16)v.x, (_Float16)v.y, (_Float16)v.z, (_Float16)v.w};
    bX = bx2e[lane & 31];
  }
  __syncthreads();
  float demov = (lane >= 32 && lane < 42) ? demoL[lane - 32] : 0.f;

  for (int ti = 0; ti < 4; ti++) {
    int t = tc * 4 + ti;
    int tok = b * TT + t;
    const float* row = x + (size_t)(b * 65 + t) * XD;
    bf16_t* Frow = F + (size_t)tok * KF;

    // ---- stage1: agent-per-lane, all in registers ----
    if (lane < NAG) {
      float4 xa = *(const float4*)(row + lane * 4);
      half2_t x0{(_Float16)xa.x, (_Float16)xa.y};
      half2_t x1{(_Float16)xa.z, (_Float16)xa.w};
      float h1v[8];
#pragma unroll
      for (int o = 0; o < 8; o++) {
        float s = bA[o];
        s = fdot2f(x0, half2_t{wA[o][0], wA[o][1]}, s);
        s = fdot2f(x1, half2_t{wA[o][2], wA[o][3]}, s);
        h1v[o] = elu_fast(s);
      }
      half2_t e0{(_Float16)h1v[0], (_Float16)h1v[1]};
      half2_t e1{(_Float16)h1v[2], (_Float16)h1v[3]};
      half2_t e2{(_Float16)h1v[4], (_Float16)h1v[5]};
      half2_t e3{(_Float16)h1v[6], (_Float16)h1v[7]};
      half8_t hout;
#pragma unroll
      for (int o = 0; o < 8; o++) {
        float s = bB1[o];
        s = fdot2f(e0, half2_t{wB1[o][0], wB1[o][1]}, s);
        s = fdot2f(e1, half2_t{wB1[o][2], wB1[o][3]}, s);
        s = fdot2f(e2, half2_t{wB1[o][4], wB1[o][5]}, s);
        s = fdot2f(e3, half2_t{wB1[o][6], wB1[o][7]}, s);
        hout[o] = (_Float16)elu_fast(s);
      }
      *(half8_t*)&h1sp[lane * 8] = hout;
    }
    __syncthreads();

    // ---- stage2 + gemb fused, edge-per-lane ----
#pragma unroll
    for (int q = 0; q < 2; q++) {
      int e = lane + 64 * q;
      if (e < NEDGE) {
        int r = (e * 57) >> 9;               // e/9 for e<90
        int sd = e - 9 * r;
        sd += (sd >= r) ? 1 : 0;
        half8_t hr = *(const half8_t*)&h1sp[r * 8];
        half8_t hs = *(const half8_t*)&h1sp[sd * 8];
        float av[8];
#pragma unroll
        for (int o = 0; o < 8; o++) {
          half8_t wr8 = *(const half8_t*)&w2aR[o * 8];
          half8_t ws8 = *(const half8_t*)&w2aS[o * 8];
          float s = bR[o];
          s = dot8h(hr, wr8, s);
          s = dot8h(hs, ws8, s);
          av[o] = elu_fast(s);
        }
        half2_t a0{(_Float16)av[0], (_Float16)av[1]};
        half2_t a1{(_Float16)av[2], (_Float16)av[3]};
        half2_t a2{(_Float16)av[4], (_Float16)av[5]};
        half2_t a3{(_Float16)av[6], (_Float16)av[7]};
        union { bf16_t h[8]; uint4 u; } pk;
#pragma unroll
        for (int o = 0; o < 8; o++) {
          half8_t wb8 = *(const half8_t*)&w2bp[o * 8];
          float s = bG[o];
          s = fdot2f(a0, half2_t{wb8[0], wb8[1]}, s);
          s = fdot2f(a1, half2_t{wb8[2], wb8[3]}, s);
          s = fdot2f(a2, half2_t{wb8[4], wb8[5]}, s);
          s = fdot2f(a3, half2_t{wb8[6], wb8[7]}, s);
          pk.h[o] = (bf16_t)elu_fast(s);
        }
        *(uint4*)(Frow + 48 + e * 8) = pk.u;   // 16B aligned (48*2 + e*16)
      }
    }

    // ---- xemb / demo / treat / pad ----
    float4 xe = *(const float4*)(row + XP);
    if (lane < 32) {
      float s = bX;
      s = fdot2f(half2_t{(_Float16)xe.x, (_Float16)xe.y}, half2_t{wX[0], wX[1]}, s);
      s = fdot2f(half2_t{(_Float16)xe.z, (_Float16)xe.w}, half2_t{wX[2], wX[3]}, s);
      Frow[lane] = (bf16_t)s;
    } else if (lane < 42) {
      Frow[lane] = (bf16_t)demov;
    } else if (lane == 42) {
      Frow[42] = (bf16_t)ftreat[b * 65 + t];
    } else if (lane < 48) {
      Frow[lane] = (bf16_t)0.f;
    }
    __syncthreads();   // h1sp reused next token
  }
}

// ---------------------------------------------------------------------------
// Kernel 3: G[16384,640] = F[16384,768] @ WT^T + bcat  (bf16 MFMA, fp32 acc)
// ---------------------------------------------------------------------------
__global__ __launch_bounds__(256) void gemm_kernel(
    const bf16_t* __restrict__ F, const bf16_t* __restrict__ WT,
    const float* __restrict__ bcat, float* __restrict__ G) {
  __shared__ __align__(16) bf16_t As[128 * 32];
  __shared__ __align__(16) bf16_t Bs[128 * 32];

  int tid  = threadIdx.x;
  int lane = tid & 63;
  int wv   = tid >> 6;
  int wr   = wv >> 1, wc = wv & 1;
  int m0 = blockIdx.x * 128, n0 = blockIdx.y * 128;

  floatx4 acc[4][4];
#pragma unroll
  for (int i = 0; i < 4; i++)
#pragma unroll
    for (int j = 0; j < 4; j++) acc[i][j] = floatx4{0.f, 0.f, 0.f, 0.f};

  int c0 = tid, c1 = tid + 256;
  int r0 = c0 >> 2, p0 = c0 & 3;
  int r1 = c1 >> 2, p1 = c1 & 3;
  int qr = lane >> 4;
  int lr = lane & 15;

  for (int k0 = 0; k0 < KF; k0 += 32) {
    uint4 a0 = *(const uint4*)(F  + (size_t)(m0 + r0) * KF + k0 + p0 * 8);
    uint4 a1 = *(const uint4*)(F  + (size_t)(m0 + r1) * KF + k0 + p1 * 8);
    uint4 b0 = *(const uint4*)(WT + (size_t)(n0 + r0) * KF + k0 + p0 * 8);
    uint4 b1 = *(const uint4*)(WT + (size_t)(n0 + r1) * KF + k0 + p1 * 8);
    __syncthreads();
    ((uint4*)As)[c0] = a0; ((uint4*)As)[c1] = a1;
    ((uint4*)Bs)[c0] = b0; ((uint4*)Bs)[c1] = b1;
    __syncthreads();

    bf16x8 af[4], bf[4];
#pragma unroll
    for (int i = 0; i < 4; i++) {
      af[i] = *(const bf16x8*)(As + (wr * 64 + i * 16 + lr) * 32 + qr * 8);
      bf[i] = *(const bf16x8*)(Bs + (wc * 64 + i * 16 + lr) * 32 + qr * 8);
    }
#pragma unroll
    for (int i = 0; i < 4; i++)
#pragma unroll
      for (int j = 0; j < 4; j++)
        acc[i][j] = __builtin_amdgcn_mfma_f32_16x16x32_bf16(af[i], bf[j], acc[i][j], 0, 0, 0);
  }

#pragma unroll
  for (int i = 0; i < 4; i++) {
#pragma unroll
    for (int j = 0; j < 4; j++) {
      int col = n0 + wc * 64 + j * 16 + lr;
      float bv = bcat[col];
#pragma unroll
      for (int r = 0; r < 4; r++) {
        int row = m0 + wr * 64 + i * 16 + qr * 4 + r;
        G[(size_t)row * NTOT + col] = acc[i][j][r] + bv;
      }
    }
  }
}

// ---------------------------------------------------------------------------
// Kernel 4: heads — a_out / y_out (one wave per token)
// ---------------------------------------------------------------------------
__global__ __launch_bounds__(256) void head_kernel(
    const float* __restrict__ G, const float* __restrict__ Wa2,
    const float* __restrict__ Wo2, float* __restrict__ out) {
  int wid  = (blockIdx.x * 256 + threadIdx.x) >> 6;
  int lane = threadIdx.x & 63;
  const float* g = G + (size_t)wid * NTOT;
  float sa = fmaxf(g[lane], 0.f) * Wa2[lane] + fmaxf(g[lane + 64], 0.f) * Wa2[lane + 64];
  float sy = fmaxf(g[128 + lane], 0.f) * Wo2[lane] + fmaxf(g[192 + lane], 0.f) * Wo2[lane + 64];
#pragma unroll
  for (int off = 32; off > 0; off >>= 1) {
    sa += __shfl_down(sa, off, 64);
    sy += __shfl_down(sy, off, 64);
  }
  if (lane == 0) {
    out[(size_t)wid * 130 + 0] = sa;
    out[(size_t)wid * 130 + 1] = sy;
  }
}

// ---------------------------------------------------------------------------
// Kernel 5: GRU — 1 block (128 threads, 2 waves) per sequence. (R4 version)
// ---------------------------------------------------------------------------
__global__ __launch_bounds__(128, 2) void gru_kernel(
    const float* __restrict__ G, const float* __restrict__ h0,
    const float* __restrict__ Whh, const float* __restrict__ bhh,
    float* __restrict__ out) {
  int b = blockIdx.x;
  int tid = threadIdx.x;          // 0..127 == hidden unit j
  int lane = tid & 63;

  __shared__ unsigned int h2[2][HID / 2];

  const float* gbase = G + (size_t)b * TT * NTOT;

  half2_t wr[64], wz[64], wn[64];
#pragma unroll
  for (int l = 0; l < 64; l++) {
    float2 a = *(const float2*)(Whh + (size_t)tid * HID + 2 * l);
    wr[l] = half2_t{(_Float16)a.x, (_Float16)a.y};
  }
#pragma unroll
  for (int l = 0; l < 64; l++) {
    float2 a = *(const float2*)(Whh + (size_t)(HID + tid) * HID + 2 * l);
    wz[l] = half2_t{(_Float16)a.x, (_Float16)a.y};
  }
#pragma unroll
  for (int l = 0; l < 64; l++) {
    float2 a = *(const float2*)(Whh + (size_t)(2 * HID + tid) * HID + 2 * l);
    wn[l] = half2_t{(_Float16)a.x, (_Float16)a.y};
  }
  float br = bhh[tid], bz = bhh[HID + tid], bn = bhh[2 * HID + tid];

  float hprev = h0[(size_t)b * HID + tid];
  ((_Float16*)h2[0])[tid] = (_Float16)hprev;
  float ir = gbase[256 + tid], iz = gbase[384 + tid], inn = gbase[512 + tid];
  __syncthreads();

  for (int t = 0; t < TT; t++) {
    unsigned int hl = h2[t & 1][lane];
    float nir = 0.f, niz = 0.f, ninn = 0.f;
    if (t + 1 < TT) {
      const float* gn = gbase + (size_t)(t + 1) * NTOT;
      nir  = gn[256 + tid];
      niz  = gn[384 + tid];
      ninn = gn[512 + tid];
    }
    float sr0 = 0.f, sr1 = 0.f, sz0 = 0.f, sz1 = 0.f, sn0 = 0.f, sn1 = 0.f;
#pragma unroll
    for (int l = 0; l < 64; l += 2) {
      int p0 = __builtin_amdgcn_readlane((int)hl, l);
      int p1 = __builtin_amdgcn_readlane((int)hl, l + 1);
      half2_t q0 = __builtin_bit_cast(half2_t, p0);
      half2_t q1 = __builtin_bit_cast(half2_t, p1);
      sr0 = __builtin_amdgcn_fdot2(wr[l],     q0, sr0, false);
      sr1 = __builtin_amdgcn_fdot2(wr[l + 1], q1, sr1, false);
      sz0 = __builtin_amdgcn_fdot2(wz[l],     q0, sz0, false);
      sz1 = __builtin_amdgcn_fdot2(wz[l + 1], q1, sz1, false);
      sn0 = __builtin_amdgcn_fdot2(wn[l],     q0, sn0, false);
      sn1 = __builtin_amdgcn_fdot2(wn[l + 1], q1, sn1, false);
    }
    float r  = sigmoid_fast(ir + sr0 + sr1 + br);
    float z  = sigmoid_fast(iz + sz0 + sz1 + bz);
    float nn = tanh_fast(inn + r * (sn0 + sn1 + bn));
    float hn = (1.f - z) * nn + z * hprev;
    hprev = hn;
    ((_Float16*)h2[(t + 1) & 1])[tid] = (_Float16)hn;
    __syncthreads();
    out[(size_t)(b * TT + t) * 130 + 2 + tid] = hn;
    ir = nir; iz = niz; inn = ninn;
  }
}

// ---------------------------------------------------------------------------
extern "C" void kernel_launch(void* const* d_in, const int* in_sizes, int n_in,
                              void* d_out, int out_size, void* d_ws, size_t ws_size,
                              hipStream_t stream) {
  const float* x      = (const float*)d_in[0];
  const float* x_demo = (const float*)d_in[1];
  const float* ftr    = (const float*)d_in[2];
  const float* h0     = (const float*)d_in[3];
  const float* Wx2e   = (const float*)d_in[4];
  const float* bx2e   = (const float*)d_in[5];
  const float* Wst    = (const float*)d_in[6];
  const float* bst    = (const float*)d_in[7];
  const float* Wm1a   = (const float*)d_in[8];
  const float* bm1a   = (const float*)d_in[9];
  const float* Wm1b   = (const float*)d_in[10];
  const float* bm1b   = (const float*)d_in[11];
  const float* Wm2a   = (const float*)d_in[12];
  const float* bm2a   = (const float*)d_in[13];
  const float* Wm2b   = (const float*)d_in[14];
  const float* bm2b   = (const float*)d_in[15];
  const float* Wa1    = (const float*)d_in[16];
  const float* ba1    = (const float*)d_in[17];
  const float* Wa2    = (const float*)d_in[18];
  const float* Wo1    = (const float*)d_in[19];
  const float* bo1    = (const float*)d_in[20];
  const float* Wo2    = (const float*)d_in[21];
  const float* Wih    = (const float*)d_in[22];
  const float* bih    = (const float*)d_in[23];
  const float* Whh    = (const float*)d_in[24];
  const float* bhh    = (const float*)d_in[25];
  float* out = (float*)d_out;

  char* ws = (char*)d_ws;
  bf16_t* F   = (bf16_t*)(ws);                             // 25165824 B
  bf16_t* WT  = (bf16_t*)(ws + 25165824);                  // 983040 B
  float*  bc  = (float*)(ws + 25165824 + 983040);          // 2560 B
  float*  G   = (float*)(ws + 25165824 + 983040 + 2560);   // 41943040 B

  prep_kernel<<<dim3((NTOT * KF + 255) / 256), dim3(256), 0, stream>>>(
      Wa1, ba1, Wo1, bo1, Wih, bih, WT, bc);
  encoder_kernel<<<dim3(BB * 16), dim3(64), 0, stream>>>(
      x, x_demo, ftr, Wm1a, bm1a, Wm1b, bm1b, Wm2a, bm2a, Wm2b, bm2b,
      Wx2e, bx2e, Wst, bst, F);
  gemm_kernel<<<dim3(BT / 128, NTOT / 128), dim3(256), 0, stream>>>(F, WT, bc, G);
  head_kernel<<<dim3(BT / 4), dim3(256), 0, stream>>>(G, Wa2, Wo2, out);
  gru_kernel<<<dim3(BB), dim3(128), 0, stream>>>(G, h0, Whh, bhh, out);
}